// Round 3
// baseline (482.971 us; speedup 1.0000x reference)
//
#include <hip/hip_runtime.h>
#include <hip/hip_bf16.h>
#include <stdint.h>

#define HID 256
#define BATCH 64
#define SEQ 4096

typedef __attribute__((ext_vector_type(8))) short bf16x8;
typedef __attribute__((ext_vector_type(4))) short short4v;
typedef __attribute__((ext_vector_type(4))) float f32x4;

static __device__ __forceinline__ unsigned short f2bf(float f) {
    union { float f; uint32_t u; } v; v.f = f;
    uint32_t u = v.u;
    return (unsigned short)((u + 0x7FFF + ((u >> 16) & 1)) >> 16);  // RNE
}

static __device__ __forceinline__ float fast_tanh(float x) {
    float cx = fminf(fmaxf(x, -15.f), 15.f);
    float e = __expf(2.f * cx);
    return (e - 1.f) / (e + 1.f);
}

// ---------------- prep: WFt[c][h] = bf16(W_F[h][c]) ----------------
__global__ __launch_bounds__(256) void prep_wft(const float* __restrict__ WF,
                                                unsigned short* __restrict__ WFt) {
    int c = blockIdx.x, h = threadIdx.x;
    WFt[c * HID + h] = f2bf(WF[h * HID + c]);
}

// ---------------- prep: u_t[b][h] = sum_k W_t[h][k] * o_last[b][k] ----------------
__global__ __launch_bounds__(256) void prep_ut(const float* __restrict__ o,
                                               const float* __restrict__ Wt,
                                               float* __restrict__ ut) {
    __shared__ float ol[HID];
    int b = blockIdx.x, h = threadIdx.x;
    ol[h] = o[(size_t)(b * SEQ + SEQ - 1) * HID + h];
    __syncthreads();
    const float* wrow = Wt + h * HID;
    float acc = 0.f;
    #pragma unroll 8
    for (int k = 0; k < HID; k++) acc += wrow[k] * ol[k];
    ut[b * HID + h] = acc;
}

// ---------------- scores: st (fp32 dot) + sf (MFMA bf16 + tanh epilogue) ----------------
// grid 4096: block = (b, s-tile of 64 rows). 4 waves, wave w owns cols w*64..+63.
__global__ __launch_bounds__(256) void scores_kernel(const float* __restrict__ o,
                                                     const unsigned short* __restrict__ WFt,
                                                     const float* __restrict__ ut,
                                                     const float* __restrict__ vF,
                                                     float* __restrict__ stOut,
                                                     float* __restrict__ sfOut) {
    __shared__ unsigned short o_sm[64 * HID];  // bf16, XOR-swizzled (32 KB)
    __shared__ float u_sm[HID];
    __shared__ float stp[64 * 64];             // fp32 st partials, swizzled (16 KB)
    __shared__ float red[4 * 64];
    __shared__ float sfr[4 * 64];

    int t = threadIdx.x;
    int lane = t & 63, w = t >> 6;
    int bid = blockIdx.x;
    int b = bid >> 6;
    int s0 = (bid & 63) << 6;

    u_sm[t] = ut[b * HID + t];
    __syncthreads();

    const float* obase = o + (size_t)(b * SEQ + s0) * HID;
    const float4 u4 = *(const float4*)&u_sm[lane << 2];

    // stage 64x256 tile: fp32 st partial + bf16 into swizzled LDS
    #pragma unroll 4
    for (int j = 0; j < 16; j++) {
        int e = j * 1024 + t * 4;
        float4 v = *(const float4*)(obase + e);
        int row = j * 4 + w;
        float d = v.x * u4.x + v.y * u4.y + v.z * u4.z + v.w * u4.w;
        stp[(row << 6) + (lane ^ (row & 31))] = d;
        int byte = (row << 9) + (lane << 3);
        byte ^= (row & 7) << 4;
        short4v sv;
        sv.x = (short)f2bf(v.x); sv.y = (short)f2bf(v.y);
        sv.z = (short)f2bf(v.z); sv.w = (short)f2bf(v.w);
        *(short4v*)((char*)o_sm + byte) = sv;
    }
    __syncthreads();

    // st partial reduction: thread (part=w, r=lane) sums 16 lanes' partials
    {
        int r = lane, part = w;
        float ssum = 0.f;
        #pragma unroll
        for (int i = 0; i < 16; i++) {
            int c = part * 16 + i;
            ssum += stp[(r << 6) + (c ^ (r & 31))];
        }
        red[part * 64 + r] = ssum;
    }

    // MFMA: 64 rows x 256 cols, K=256. wave w: cols w*64..+63 (4 col-blocks)
    f32x4 acc[4][4];
    #pragma unroll
    for (int ar = 0; ar < 4; ar++)
        #pragma unroll
        for (int cb = 0; cb < 4; cb++)
            acc[ar][cb] = (f32x4){0.f, 0.f, 0.f, 0.f};

    int cw = w << 6;
    int lm = lane & 15, lg = lane >> 4;

    #pragma unroll
    for (int kk = 0; kk < 8; kk++) {
        int h0 = kk * 32 + lg * 8;
        bf16x8 bf[4], af[4];
        #pragma unroll
        for (int cb = 0; cb < 4; cb++) {
            int c = cw + cb * 16 + lm;
            bf[cb] = *(const bf16x8*)(WFt + (size_t)c * HID + h0);
        }
        #pragma unroll
        for (int ar = 0; ar < 4; ar++) {
            int row = ar * 16 + lm;
            int byte = (row << 9) + h0 * 2;
            byte ^= (row & 7) << 4;
            af[ar] = *(const bf16x8*)((const char*)o_sm + byte);
        }
        #pragma unroll
        for (int ar = 0; ar < 4; ar++)
            #pragma unroll
            for (int cb = 0; cb < 4; cb++)
                acc[ar][cb] = __builtin_amdgcn_mfma_f32_16x16x32_bf16(af[ar], bf[cb], acc[ar][cb], 0, 0, 0);
    }

    __syncthreads();  // red[] complete for all waves
    if (t < 64) {
        float s = red[t] + red[64 + t] + red[128 + t] + red[192 + t];
        stOut[(size_t)b * SEQ + s0 + t] = s;
    }

    // epilogue: sf partial = sum_c tanh(z)*vF[c] over this wave's 64 cols
    float vf[4];
    #pragma unroll
    for (int cb = 0; cb < 4; cb++) vf[cb] = vF[cw + cb * 16 + lm];

    #pragma unroll
    for (int ar = 0; ar < 4; ar++) {
        #pragma unroll
        for (int i = 0; i < 4; i++) {
            float p = 0.f;
            #pragma unroll
            for (int cb = 0; cb < 4; cb++)
                p += fast_tanh(acc[ar][cb][i]) * vf[cb];
            // reduce over the 16 lanes (lm bits) holding different cols of same rows
            p += __shfl_xor(p, 1);
            p += __shfl_xor(p, 2);
            p += __shfl_xor(p, 4);
            p += __shfl_xor(p, 8);
            if (lm == 0) sfr[w * 64 + ar * 16 + lg * 4 + i] = p;
        }
    }
    __syncthreads();
    if (t < 64) {
        float s = sfr[t] + sfr[64 + t] + sfr[128 + t] + sfr[192 + t];
        sfOut[(size_t)b * SEQ + s0 + t] = s;
    }
}

// ---------------- softmax stats (max, sumexp) per b for both score sets ----------------
template <bool MAXOP>
static __device__ __forceinline__ float block_reduce(float v, float* sh) {
    #pragma unroll
    for (int m = 1; m < 64; m <<= 1) {
        float o = __shfl_xor(v, m);
        v = MAXOP ? fmaxf(v, o) : (v + o);
    }
    int w = threadIdx.x >> 6;
    if ((threadIdx.x & 63) == 0) sh[w] = v;
    __syncthreads();
    float r = MAXOP ? fmaxf(fmaxf(sh[0], sh[1]), fmaxf(sh[2], sh[3]))
                    : (sh[0] + sh[1] + sh[2] + sh[3]);
    __syncthreads();
    return r;
}

__global__ __launch_bounds__(256) void stats_kernel(const float* __restrict__ st,
                                                    const float* __restrict__ sf,
                                                    float* __restrict__ stats) {
    __shared__ float sh[4];
    int b = blockIdx.x, t = threadIdx.x;
    const float* pt = st + (size_t)b * SEQ;
    const float* pf = sf + (size_t)b * SEQ;
    float vt[16], vf[16], mT = -1e30f, mF = -1e30f;
    #pragma unroll
    for (int j = 0; j < 16; j++) {
        vt[j] = pt[t + j * 256]; mT = fmaxf(mT, vt[j]);
        vf[j] = pf[t + j * 256]; mF = fmaxf(mF, vf[j]);
    }
    mT = block_reduce<true>(mT, sh);
    mF = block_reduce<true>(mF, sh);
    float sT = 0.f, sF = 0.f;
    #pragma unroll
    for (int j = 0; j < 16; j++) {
        sT += __expf(vt[j] - mT);
        sF += __expf(vf[j] - mF);
    }
    sT = block_reduce<false>(sT, sh);
    sF = block_reduce<false>(sF, sh);
    if (t == 0) {
        stats[b * 4 + 0] = mT;
        stats[b * 4 + 1] = sT;
        stats[b * 4 + 2] = mF;
        stats[b * 4 + 3] = sF;
    }
}

// ---------------- output: weighted sums over s ----------------
// grid 1024 = 64 b x 16 s-chunks of 256. float4 loads, atomic combine.
__global__ __launch_bounds__(256) void out_kernel(const float* __restrict__ o,
                                                  const float* __restrict__ st,
                                                  const float* __restrict__ sf,
                                                  const float* __restrict__ stats,
                                                  float* __restrict__ out) {
    __shared__ float wT[256], wF[256];
    __shared__ float4 redT[4][64], redF[4][64];
    int bid = blockIdx.x;
    int b = bid >> 4, chunk = bid & 15, s0 = chunk << 8;
    int t = threadIdx.x;

    float mT = stats[b * 4 + 0], isT = 1.f / stats[b * 4 + 1];
    float mF = stats[b * 4 + 2], isF = 1.f / stats[b * 4 + 3];
    wT[t] = __expf(st[(size_t)b * SEQ + s0 + t] - mT) * isT;
    wF[t] = __expf(sf[(size_t)b * SEQ + s0 + t] - mF) * isF;
    __syncthreads();

    int hc = t & 63, sl = t >> 6;
    const float* ob = o + (size_t)(b * SEQ + s0) * HID + hc * 4;
    float4 aT = {0.f, 0.f, 0.f, 0.f}, aF = {0.f, 0.f, 0.f, 0.f};
    #pragma unroll 4
    for (int s = sl; s < 256; s += 4) {
        float4 v = *(const float4*)(ob + (size_t)s * HID);
        float wt = wT[s], wf = wF[s];
        aT.x += wt * v.x; aT.y += wt * v.y; aT.z += wt * v.z; aT.w += wt * v.w;
        aF.x += wf * v.x; aF.y += wf * v.y; aF.z += wf * v.z; aF.w += wf * v.w;
    }
    redT[sl][hc] = aT;
    redF[sl][hc] = aF;
    __syncthreads();

    int hcc = t >> 2, i = t & 3;
    float sumT = 0.f, sumF = 0.f;
    #pragma unroll
    for (int p = 0; p < 4; p++) {
        sumT += ((const float*)&redT[p][hcc])[i];
        sumF += ((const float*)&redF[p][hcc])[i];
    }
    atomicAdd(out + (size_t)b * 512 + t, sumT);
    atomicAdd(out + (size_t)b * 512 + 256 + t, sumF);
}

extern "C" void kernel_launch(void* const* d_in, const int* in_sizes, int n_in,
                              void* d_out, int out_size, void* d_ws, size_t ws_size,
                              hipStream_t stream) {
    const float* o  = (const float*)d_in[0];
    const float* Wt = (const float*)d_in[1];
    const float* WF = (const float*)d_in[2];
    const float* vF = (const float*)d_in[3];
    float* out = (float*)d_out;
    char* ws = (char*)d_ws;

    unsigned short* WFt = (unsigned short*)ws;                    // 128 KB
    float* ut    = (float*)(ws + 131072);                         // 64 KB
    float* stS   = (float*)(ws + 196608);                         // 1 MB
    float* sfS   = (float*)(ws + 196608 + 1048576);               // 1 MB
    float* stats = (float*)(ws + 196608 + 2097152);               // 1 KB

    hipMemsetAsync(d_out, 0, (size_t)BATCH * 512 * sizeof(float), stream);
    prep_wft<<<256, 256, 0, stream>>>(WF, WFt);
    prep_ut<<<BATCH, 256, 0, stream>>>(o, Wt, ut);
    scores_kernel<<<BATCH * 64, 256, 0, stream>>>(o, WFt, ut, vF, stS, sfS);
    stats_kernel<<<BATCH, 256, 0, stream>>>(stS, sfS, stats);
    out_kernel<<<BATCH * 16, 256, 0, stream>>>(o, stS, sfS, stats, out);
}

// Round 4
// 460.764 us; speedup vs baseline: 1.0482x; 1.0482x over previous
//
#include <hip/hip_runtime.h>
#include <hip/hip_bf16.h>
#include <stdint.h>

#define HID 256
#define BATCH 64
#define SEQ 4096

typedef __attribute__((ext_vector_type(8))) short bf16x8;
typedef __attribute__((ext_vector_type(4))) short short4v;
typedef __attribute__((ext_vector_type(4))) float f32x4;

static __device__ __forceinline__ unsigned short f2bf(float f) {
    union { float f; uint32_t u; } v; v.f = f;
    uint32_t u = v.u;
    return (unsigned short)((u + 0x7FFF + ((u >> 16) & 1)) >> 16);  // RNE
}

static __device__ __forceinline__ float fast_tanh(float x) {
    float cx = fminf(fmaxf(x, -15.f), 15.f);
    float e = __expf(2.f * cx);
    return (e - 1.f) / (e + 1.f);
}

// ---------------- prep: WFt[c][h] = bf16(W_F[h][c]) ----------------
__global__ __launch_bounds__(256) void prep_wft(const float* __restrict__ WF,
                                                unsigned short* __restrict__ WFt) {
    int c = blockIdx.x, h = threadIdx.x;
    WFt[c * HID + h] = f2bf(WF[h * HID + c]);
}

// ---------------- prep: u_t[b][h] = sum_k W_t[h][k] * o_last[b][k] ----------------
__global__ __launch_bounds__(256) void prep_ut(const float* __restrict__ o,
                                               const float* __restrict__ Wt,
                                               float* __restrict__ ut) {
    __shared__ float ol[HID];
    int b = blockIdx.x, h = threadIdx.x;
    ol[h] = o[(size_t)(b * SEQ + SEQ - 1) * HID + h];
    __syncthreads();
    const float* wrow = Wt + h * HID;
    float acc = 0.f;
    #pragma unroll 8
    for (int k = 0; k < HID; k++) acc += wrow[k] * ol[k];
    ut[b * HID + h] = acc;
}

// ---------------- scores: st (fp32 dot, shuffle-reduced) + sf (MFMA bf16 + tanh) ----
// grid 4096: block = (b, s-tile of 64 rows). 4 waves, wave w owns cols w*64..+63.
// LDS 35.25 KB -> 4 blocks/CU; __launch_bounds__(256,4) pins VGPR<=128.
__global__ __launch_bounds__(256, 4) void scores_kernel(const float* __restrict__ o,
                                                        const unsigned short* __restrict__ WFt,
                                                        const float* __restrict__ ut,
                                                        const float* __restrict__ vF,
                                                        float* __restrict__ stOut,
                                                        float* __restrict__ sfOut) {
    __shared__ unsigned short o_sm[64 * HID];  // bf16, XOR-swizzled (32 KB)
    __shared__ float u_sm[HID];                // 1 KB
    __shared__ float red_sm[64 * 4];           // st partials, 1 KB
    __shared__ float sfr[4 * 64];              // 1 KB

    int t = threadIdx.x;
    int lane = t & 63, w = t >> 6;
    int bid = blockIdx.x;
    int b = bid >> 6;
    int s0 = (bid & 63) << 6;
    int lm = lane & 15, lg = lane >> 4;

    u_sm[t] = ut[b * HID + t];
    __syncthreads();

    const float* pbase = o + (size_t)(b * SEQ + s0) * HID + t * 4;
    const float4 u4 = *(const float4*)&u_sm[lane << 2];

    // stage 64x256 tile: 2 batches of 8 float4 loads (8-16 in flight), then process
    float4 va[8], vb[8];
    #pragma unroll
    for (int j = 0; j < 8; j++) va[j] = *(const float4*)(pbase + j * 1024);
    #pragma unroll
    for (int j = 0; j < 8; j++) vb[j] = *(const float4*)(pbase + (j + 8) * 1024);

    #pragma unroll
    for (int j = 0; j < 16; j++) {
        float4 v = (j < 8) ? va[j & 7] : vb[j & 7];
        int row = j * 4 + w;
        // st partial: dot over this lane's 4 cols, then 4-level shuffle (16 lanes)
        float p = v.x * u4.x + v.y * u4.y + v.z * u4.z + v.w * u4.w;
        p += __shfl_xor(p, 1);
        p += __shfl_xor(p, 2);
        p += __shfl_xor(p, 4);
        p += __shfl_xor(p, 8);
        if (lm == 0) red_sm[(row << 2) + lg] = p;
        // bf16 into swizzled LDS
        int byte = (row << 9) + (lane << 3);
        byte ^= (row & 7) << 4;
        short4v sv;
        sv.x = (short)f2bf(v.x); sv.y = (short)f2bf(v.y);
        sv.z = (short)f2bf(v.z); sv.w = (short)f2bf(v.w);
        *(short4v*)((char*)o_sm + byte) = sv;
    }
    __syncthreads();

    if (t < 64) {
        const float* r4 = &red_sm[t << 2];
        stOut[(size_t)b * SEQ + s0 + t] = r4[0] + r4[1] + r4[2] + r4[3];
    }

    // MFMA: 64 rows x 256 cols, K=256. wave w: cols w*64..+63 (4 col-blocks)
    f32x4 acc[4][4];
    #pragma unroll
    for (int ar = 0; ar < 4; ar++)
        #pragma unroll
        for (int cb = 0; cb < 4; cb++)
            acc[ar][cb] = (f32x4){0.f, 0.f, 0.f, 0.f};

    int cw = w << 6;

    #pragma unroll
    for (int kk = 0; kk < 8; kk++) {
        int h0 = kk * 32 + lg * 8;
        bf16x8 bf[4], af[4];
        #pragma unroll
        for (int cb = 0; cb < 4; cb++) {
            int c = cw + cb * 16 + lm;
            bf[cb] = *(const bf16x8*)(WFt + (size_t)c * HID + h0);
        }
        #pragma unroll
        for (int ar = 0; ar < 4; ar++) {
            int row = ar * 16 + lm;
            int byte = (row << 9) + h0 * 2;
            byte ^= (row & 7) << 4;
            af[ar] = *(const bf16x8*)((const char*)o_sm + byte);
        }
        #pragma unroll
        for (int ar = 0; ar < 4; ar++)
            #pragma unroll
            for (int cb = 0; cb < 4; cb++)
                acc[ar][cb] = __builtin_amdgcn_mfma_f32_16x16x32_bf16(af[ar], bf[cb], acc[ar][cb], 0, 0, 0);
    }

    // epilogue: sf partial = sum_c tanh(z)*vF[c] over this wave's 64 cols
    float vf[4];
    #pragma unroll
    for (int cb = 0; cb < 4; cb++) vf[cb] = vF[cw + cb * 16 + lm];

    #pragma unroll
    for (int ar = 0; ar < 4; ar++) {
        #pragma unroll
        for (int i = 0; i < 4; i++) {
            float p = 0.f;
            #pragma unroll
            for (int cb = 0; cb < 4; cb++)
                p += fast_tanh(acc[ar][cb][i]) * vf[cb];
            p += __shfl_xor(p, 1);
            p += __shfl_xor(p, 2);
            p += __shfl_xor(p, 4);
            p += __shfl_xor(p, 8);
            if (lm == 0) sfr[w * 64 + ar * 16 + lg * 4 + i] = p;
        }
    }
    __syncthreads();
    if (t < 64) {
        float s = sfr[t] + sfr[64 + t] + sfr[128 + t] + sfr[192 + t];
        sfOut[(size_t)b * SEQ + s0 + t] = s;
    }
}

// ---------------- softmax stats (max, sumexp) per b for both score sets ----------------
template <bool MAXOP>
static __device__ __forceinline__ float block_reduce(float v, float* sh) {
    #pragma unroll
    for (int m = 1; m < 64; m <<= 1) {
        float o = __shfl_xor(v, m);
        v = MAXOP ? fmaxf(v, o) : (v + o);
    }
    int w = threadIdx.x >> 6;
    if ((threadIdx.x & 63) == 0) sh[w] = v;
    __syncthreads();
    float r = MAXOP ? fmaxf(fmaxf(sh[0], sh[1]), fmaxf(sh[2], sh[3]))
                    : (sh[0] + sh[1] + sh[2] + sh[3]);
    __syncthreads();
    return r;
}

__global__ __launch_bounds__(256) void stats_kernel(const float* __restrict__ st,
                                                    const float* __restrict__ sf,
                                                    float* __restrict__ stats) {
    __shared__ float sh[4];
    int b = blockIdx.x, t = threadIdx.x;
    const float* pt = st + (size_t)b * SEQ;
    const float* pf = sf + (size_t)b * SEQ;
    float vt[16], vf[16], mT = -1e30f, mF = -1e30f;
    #pragma unroll
    for (int j = 0; j < 16; j++) {
        vt[j] = pt[t + j * 256]; mT = fmaxf(mT, vt[j]);
        vf[j] = pf[t + j * 256]; mF = fmaxf(mF, vf[j]);
    }
    mT = block_reduce<true>(mT, sh);
    mF = block_reduce<true>(mF, sh);
    float sT = 0.f, sF = 0.f;
    #pragma unroll
    for (int j = 0; j < 16; j++) {
        sT += __expf(vt[j] - mT);
        sF += __expf(vf[j] - mF);
    }
    sT = block_reduce<false>(sT, sh);
    sF = block_reduce<false>(sF, sh);
    if (t == 0) {
        stats[b * 4 + 0] = mT;
        stats[b * 4 + 1] = sT;
        stats[b * 4 + 2] = mF;
        stats[b * 4 + 3] = sF;
    }
}

// ---------------- output: weighted sums over s ----------------
// grid 2048 = 64 b x 32 s-chunks of 128. 8 blocks/CU; 8 float4 loads in flight.
__global__ __launch_bounds__(256, 4) void out_kernel(const float* __restrict__ o,
                                                     const float* __restrict__ st,
                                                     const float* __restrict__ sf,
                                                     const float* __restrict__ stats,
                                                     float* __restrict__ out) {
    __shared__ float wT[128], wF[128];
    __shared__ float4 redT[4][64], redF[4][64];
    int bid = blockIdx.x;
    int b = bid >> 5, chunk = bid & 31, s0 = chunk << 7;
    int t = threadIdx.x;

    if (t < 128) {
        float mT = stats[b * 4 + 0], isT = 1.f / stats[b * 4 + 1];
        float mF = stats[b * 4 + 2], isF = 1.f / stats[b * 4 + 3];
        wT[t] = __expf(st[(size_t)b * SEQ + s0 + t] - mT) * isT;
        wF[t] = __expf(sf[(size_t)b * SEQ + s0 + t] - mF) * isF;
    }
    __syncthreads();

    int hc = t & 63, sl = t >> 6;
    const float* ob = o + (size_t)(b * SEQ + s0) * HID + hc * 4;
    float4 aT = {0.f, 0.f, 0.f, 0.f}, aF = {0.f, 0.f, 0.f, 0.f};
    // 32 rows per thread (sl + 4i), 4 batches of 8 in-flight float4 loads
    #pragma unroll
    for (int ii = 0; ii < 4; ii++) {
        float4 v[8];
        #pragma unroll
        for (int k = 0; k < 8; k++) {
            int r = sl + (ii * 8 + k) * 4;
            v[k] = *(const float4*)(ob + (size_t)r * HID);
        }
        #pragma unroll
        for (int k = 0; k < 8; k++) {
            int r = sl + (ii * 8 + k) * 4;
            float wt = wT[r], wf = wF[r];
            aT.x += wt * v[k].x; aT.y += wt * v[k].y; aT.z += wt * v[k].z; aT.w += wt * v[k].w;
            aF.x += wf * v[k].x; aF.y += wf * v[k].y; aF.z += wf * v[k].z; aF.w += wf * v[k].w;
        }
    }
    redT[sl][hc] = aT;
    redF[sl][hc] = aF;
    __syncthreads();

    int hcc = t >> 2, i = t & 3;
    float sumT = 0.f, sumF = 0.f;
    #pragma unroll
    for (int p = 0; p < 4; p++) {
        sumT += ((const float*)&redT[p][hcc])[i];
        sumF += ((const float*)&redF[p][hcc])[i];
    }
    atomicAdd(out + (size_t)b * 512 + t, sumT);
    atomicAdd(out + (size_t)b * 512 + 256 + t, sumF);
}

extern "C" void kernel_launch(void* const* d_in, const int* in_sizes, int n_in,
                              void* d_out, int out_size, void* d_ws, size_t ws_size,
                              hipStream_t stream) {
    const float* o  = (const float*)d_in[0];
    const float* Wt = (const float*)d_in[1];
    const float* WF = (const float*)d_in[2];
    const float* vF = (const float*)d_in[3];
    float* out = (float*)d_out;
    char* ws = (char*)d_ws;

    unsigned short* WFt = (unsigned short*)ws;                    // 128 KB
    float* ut    = (float*)(ws + 131072);                         // 64 KB
    float* stS   = (float*)(ws + 196608);                         // 1 MB
    float* sfS   = (float*)(ws + 196608 + 1048576);               // 1 MB
    float* stats = (float*)(ws + 196608 + 2097152);               // 1 KB

    hipMemsetAsync(d_out, 0, (size_t)BATCH * 512 * sizeof(float), stream);
    prep_wft<<<256, 256, 0, stream>>>(WF, WFt);
    prep_ut<<<BATCH, 256, 0, stream>>>(o, Wt, ut);
    scores_kernel<<<BATCH * 64, 256, 0, stream>>>(o, WFt, ut, vF, stS, sfS);
    stats_kernel<<<BATCH, 256, 0, stream>>>(stS, sfS, stats);
    out_kernel<<<BATCH * 32, 256, 0, stream>>>(o, stS, sfS, stats, out);
}

// Round 5
// 452.264 us; speedup vs baseline: 1.0679x; 1.0188x over previous
//
#include <hip/hip_runtime.h>
#include <hip/hip_bf16.h>
#include <stdint.h>

#define HID 256
#define BATCH 64
#define SEQ 4096

typedef __attribute__((ext_vector_type(8))) short bf16x8;
typedef __attribute__((ext_vector_type(4))) short short4v;
typedef __attribute__((ext_vector_type(4))) float f32x4;

static __device__ __forceinline__ unsigned short f2bf(float f) {
    union { float f; uint32_t u; } v; v.f = f;
    uint32_t u = v.u;
    return (unsigned short)((u + 0x7FFF + ((u >> 16) & 1)) >> 16);  // RNE
}

static __device__ __forceinline__ float bf2f(unsigned short b) {
    union { uint32_t u; float f; } v; v.u = ((uint32_t)b) << 16;
    return v.f;
}

static __device__ __forceinline__ float fast_tanh(float x) {
    float cx = fminf(fmaxf(x, -15.f), 15.f);
    float e = __expf(2.f * cx);
    return (e - 1.f) / (e + 1.f);
}

// ---------------- prep (merged): blocks 0..255 -> WFt col; 256..319 -> ut row ------
__global__ __launch_bounds__(256) void prep_kernel(const float* __restrict__ WF,
                                                   const float* __restrict__ Wt,
                                                   const float* __restrict__ o,
                                                   unsigned short* __restrict__ WFt,
                                                   float* __restrict__ ut) {
    __shared__ float ol[HID];
    int bid = blockIdx.x, t = threadIdx.x;
    if (bid < 256) {
        // WFt[c][h] = bf16(W_F[h][c])
        WFt[bid * HID + t] = f2bf(WF[t * HID + bid]);
    } else {
        int b = bid - 256;
        ol[t] = o[(size_t)(b * SEQ + SEQ - 1) * HID + t];
        __syncthreads();
        const float* wrow = Wt + t * HID;
        float acc = 0.f;
        #pragma unroll 16
        for (int k = 0; k < HID; k += 4) {
            float4 w4 = *(const float4*)(wrow + k);
            float4 o4 = *(const float4*)(ol + k);
            acc += w4.x * o4.x + w4.y * o4.y + w4.z * o4.z + w4.w * o4.w;
        }
        ut[b * HID + t] = acc;
    }
}

// ---------------- fused: stage tile once -> st + sf + local softmax + partials -----
// grid 4096 = 64 b x 64 chunks of 64 rows. 4 waves; wave w owns cols w*64..+63 (MFMA).
// LDS 36.3 KB -> 4 blocks/CU. Writes per-chunk stats (m,l for T/F) + weighted
// partial sums pT/pF[256] (un-normalized, local-max-referenced).
__global__ __launch_bounds__(256, 4) void fused_kernel(const float* __restrict__ o,
                                                       const unsigned short* __restrict__ WFt,
                                                       const float* __restrict__ ut,
                                                       const float* __restrict__ vF,
                                                       float* __restrict__ pT,
                                                       float* __restrict__ pF,
                                                       float* __restrict__ stats4) {
    __shared__ __align__(16) unsigned short o_sm[64 * HID];  // 32 KB, XOR-swizzled
    __shared__ float u_sm[HID];     // 1 KB
    __shared__ float red_sm[256];   // st partials [row][lg], 1 KB
    __shared__ float sfr[256];      // sf partials [w][64], 1 KB
    __shared__ float st_sm[64], sf_sm[64], wT_sm[64], wF_sm[64];  // 1 KB

    int t = threadIdx.x;
    int lane = t & 63, w = t >> 6;
    int bid = blockIdx.x;
    int b = bid >> 6;
    int s0 = (bid & 63) << 6;
    int lm = lane & 15, lg = lane >> 4;

    u_sm[t] = ut[b * HID + t];
    __syncthreads();

    const float* pbase = o + (size_t)(b * SEQ + s0) * HID + t * 4;
    const float4 u4 = *(const float4*)&u_sm[lane << 2];

    // ---- phase 1: stage 64x256 tile (2 batches of 8 in-flight float4 loads) ----
    float4 va[8], vb[8];
    #pragma unroll
    for (int j = 0; j < 8; j++) va[j] = *(const float4*)(pbase + j * 1024);
    #pragma unroll
    for (int j = 0; j < 8; j++) vb[j] = *(const float4*)(pbase + (j + 8) * 1024);

    #pragma unroll
    for (int j = 0; j < 16; j++) {
        float4 v = (j < 8) ? va[j & 7] : vb[j & 7];
        int row = j * 4 + w;
        float p = v.x * u4.x + v.y * u4.y + v.z * u4.z + v.w * u4.w;
        p += __shfl_xor(p, 1);
        p += __shfl_xor(p, 2);
        p += __shfl_xor(p, 4);
        p += __shfl_xor(p, 8);
        if (lm == 0) red_sm[(row << 2) + lg] = p;
        int byte = (row << 9) + (lane << 3);
        byte ^= (row & 7) << 4;
        short4v sv;
        sv.x = (short)f2bf(v.x); sv.y = (short)f2bf(v.y);
        sv.z = (short)f2bf(v.z); sv.w = (short)f2bf(v.w);
        *(short4v*)((char*)o_sm + byte) = sv;
    }
    __syncthreads();

    if (t < 64) {
        const float* r4 = &red_sm[t << 2];
        st_sm[t] = r4[0] + r4[1] + r4[2] + r4[3];
    }

    // ---- phase 2: MFMA 64x256, K=256 ----
    f32x4 acc[4][4];
    #pragma unroll
    for (int ar = 0; ar < 4; ar++)
        #pragma unroll
        for (int cb = 0; cb < 4; cb++)
            acc[ar][cb] = (f32x4){0.f, 0.f, 0.f, 0.f};

    int cw = w << 6;
    #pragma unroll
    for (int kk = 0; kk < 8; kk++) {
        int h0 = kk * 32 + lg * 8;
        bf16x8 bf[4], af[4];
        #pragma unroll
        for (int cb = 0; cb < 4; cb++) {
            int c = cw + cb * 16 + lm;
            bf[cb] = *(const bf16x8*)(WFt + (size_t)c * HID + h0);
        }
        #pragma unroll
        for (int ar = 0; ar < 4; ar++) {
            int row = ar * 16 + lm;
            int byte = (row << 9) + h0 * 2;
            byte ^= (row & 7) << 4;
            af[ar] = *(const bf16x8*)((const char*)o_sm + byte);
        }
        #pragma unroll
        for (int ar = 0; ar < 4; ar++)
            #pragma unroll
            for (int cb = 0; cb < 4; cb++)
                acc[ar][cb] = __builtin_amdgcn_mfma_f32_16x16x32_bf16(af[ar], bf[cb], acc[ar][cb], 0, 0, 0);
    }

    // ---- phase 3: tanh epilogue -> sf row sums ----
    float vf[4];
    #pragma unroll
    for (int cb = 0; cb < 4; cb++) vf[cb] = vF[cw + cb * 16 + lm];

    #pragma unroll
    for (int ar = 0; ar < 4; ar++) {
        #pragma unroll
        for (int i = 0; i < 4; i++) {
            float p = 0.f;
            #pragma unroll
            for (int cb = 0; cb < 4; cb++)
                p += fast_tanh(acc[ar][cb][i]) * vf[cb];
            p += __shfl_xor(p, 1);
            p += __shfl_xor(p, 2);
            p += __shfl_xor(p, 4);
            p += __shfl_xor(p, 8);
            if (lm == 0) sfr[w * 64 + ar * 16 + lg * 4 + i] = p;
        }
    }
    __syncthreads();
    if (t < 64) sf_sm[t] = sfr[t] + sfr[64 + t] + sfr[128 + t] + sfr[192 + t];
    __syncthreads();

    // ---- phase 4: local softmax stats (wave 0), un-normalized weights ----
    if (t < 64) {
        float vT = st_sm[t], vfv = sf_sm[t];
        float mT = vT, mF = vfv;
        #pragma unroll
        for (int d = 1; d < 64; d <<= 1) {
            mT = fmaxf(mT, __shfl_xor(mT, d));
            mF = fmaxf(mF, __shfl_xor(mF, d));
        }
        float wT = __expf(vT - mT), wF = __expf(vfv - mF);
        wT_sm[t] = wT; wF_sm[t] = wF;
        float lT = wT, lF = wF;
        #pragma unroll
        for (int d = 1; d < 64; d <<= 1) {
            lT += __shfl_xor(lT, d);
            lF += __shfl_xor(lF, d);
        }
        if (t == 0) {
            float* s4 = stats4 + (size_t)bid * 4;
            s4[0] = mT; s4[1] = lT; s4[2] = mF; s4[3] = lF;
        }
    }
    __syncthreads();

    // ---- phase 5: weighted partial sums from LDS tile (bf16) ----
    float4 aT = {0.f, 0.f, 0.f, 0.f}, aF = {0.f, 0.f, 0.f, 0.f};
    #pragma unroll
    for (int j = 0; j < 16; j++) {
        int row = j * 4 + w;
        int byte = (row << 9) + (lane << 3);
        byte ^= (row & 7) << 4;
        short4v sv = *(const short4v*)((const char*)o_sm + byte);
        float x0 = bf2f((unsigned short)sv.x), x1 = bf2f((unsigned short)sv.y);
        float x2 = bf2f((unsigned short)sv.z), x3 = bf2f((unsigned short)sv.w);
        float wt = wT_sm[row], wf = wF_sm[row];
        aT.x += wt * x0; aT.y += wt * x1; aT.z += wt * x2; aT.w += wt * x3;
        aF.x += wf * x0; aF.y += wf * x1; aF.z += wf * x2; aF.w += wf * x3;
    }
    __syncthreads();  // all o_sm reads done; now alias its space for reduction
    float4* pTa = (float4*)&o_sm[0];     // 4 KB
    float4* pFa = (float4*)&o_sm[2048];  // 4 KB
    pTa[w * 64 + lane] = aT;
    pFa[w * 64 + lane] = aF;
    __syncthreads();

    if (t < 64) {
        float4 s = pTa[t];
        #pragma unroll
        for (int ww = 1; ww < 4; ww++) {
            float4 q = pTa[ww * 64 + t];
            s.x += q.x; s.y += q.y; s.z += q.z; s.w += q.w;
        }
        *(float4*)(pT + (size_t)bid * HID + (t << 2)) = s;
    } else if (t < 128) {
        int tt = t - 64;
        float4 s = pFa[tt];
        #pragma unroll
        for (int ww = 1; ww < 4; ww++) {
            float4 q = pFa[ww * 64 + tt];
            s.x += q.x; s.y += q.y; s.z += q.z; s.w += q.w;
        }
        *(float4*)(pF + (size_t)bid * HID + (tt << 2)) = s;
    }
}

// ---------------- combine: rescale chunk partials -> final output ----------------
__global__ __launch_bounds__(256) void combine_kernel(const float* __restrict__ pT,
                                                      const float* __restrict__ pF,
                                                      const float* __restrict__ stats4,
                                                      float* __restrict__ out) {
    __shared__ float sMT[64], sLT[64], sMF[64], sLF[64], eT[64], eF[64];
    __shared__ float sc[2];
    int b = blockIdx.x, t = threadIdx.x;
    if (t < 64) {
        const float* s4 = stats4 + (size_t)(b * 64 + t) * 4;
        sMT[t] = s4[0]; sLT[t] = s4[1]; sMF[t] = s4[2]; sLF[t] = s4[3];
    }
    __syncthreads();
    if (t < 64) {
        float mT = sMT[t], mF = sMF[t];
        #pragma unroll
        for (int d = 1; d < 64; d <<= 1) {
            mT = fmaxf(mT, __shfl_xor(mT, d));
            mF = fmaxf(mF, __shfl_xor(mF, d));
        }
        float wT = __expf(sMT[t] - mT), wF = __expf(sMF[t] - mF);
        eT[t] = wT; eF[t] = wF;
        float lT = wT * sLT[t], lF = wF * sLF[t];
        #pragma unroll
        for (int d = 1; d < 64; d <<= 1) {
            lT += __shfl_xor(lT, d);
            lF += __shfl_xor(lF, d);
        }
        if (t == 0) { sc[0] = lT; sc[1] = lF; }
    }
    __syncthreads();
    float accT = 0.f, accF = 0.f;
    const float* pTb = pT + (size_t)b * 64 * HID + t;
    const float* pFb = pF + (size_t)b * 64 * HID + t;
    #pragma unroll 8
    for (int c = 0; c < 64; c++) {
        accT += eT[c] * pTb[(size_t)c * HID];
        accF += eF[c] * pFb[(size_t)c * HID];
    }
    out[b * 512 + t] = accT / sc[0];
    out[b * 512 + 256 + t] = accF / sc[1];
}

extern "C" void kernel_launch(void* const* d_in, const int* in_sizes, int n_in,
                              void* d_out, int out_size, void* d_ws, size_t ws_size,
                              hipStream_t stream) {
    const float* o  = (const float*)d_in[0];
    const float* Wt = (const float*)d_in[1];
    const float* WF = (const float*)d_in[2];
    const float* vF = (const float*)d_in[3];
    float* out = (float*)d_out;
    char* ws = (char*)d_ws;

    unsigned short* WFt = (unsigned short*)ws;                    // 128 KB
    float* ut     = (float*)(ws + 131072);                        // 64 KB
    float* pT     = (float*)(ws + 196608);                        // 4 MB (64b x 64c x 256h)
    float* pF     = (float*)(ws + 196608 + 4194304);              // 4 MB
    float* stats4 = (float*)(ws + 196608 + 8388608);              // 64 KB

    prep_kernel<<<320, 256, 0, stream>>>(WF, Wt, o, WFt, ut);
    fused_kernel<<<BATCH * 64, 256, 0, stream>>>(o, WFt, ut, vF, pT, pF, stats4);
    combine_kernel<<<BATCH, 256, 0, stream>>>(pT, pF, stats4, out);
}